// Round 5
// baseline (884.657 us; speedup 1.0000x reference)
//
#include <hip/hip_runtime.h>
#include <hip/hip_bf16.h>
#include <math.h>

#define BM 128
#define BN 128
#define BK 64

typedef __bf16 bf16x8_t __attribute__((ext_vector_type(8)));
typedef __bf16 bf16x4_t __attribute__((ext_vector_type(4)));
typedef float f32x16_t __attribute__((ext_vector_type(16)));

static __device__ __forceinline__ float bf2f(__bf16 b) {
    unsigned short s = __builtin_bit_cast(unsigned short, b);
    unsigned int u = ((unsigned int)s) << 16;
    return __builtin_bit_cast(float, u);
}
static __device__ __forceinline__ __bf16 f2bf(float f) {
    unsigned int u = __builtin_bit_cast(unsigned int, f);
    unsigned int r = (u + 0x7fffu + ((u >> 16) & 1u)) >> 16;
    return __builtin_bit_cast(__bf16, (unsigned short)r);
}
// GELU tanh-form, |err vs exact| ~1e-3 << 4e-2 tolerance.
static __device__ __forceinline__ float gelu_fast(float x) {
    const float s = x * (0.7978845608f + 0.0356774081f * x * x);
    const float e = __expf(-2.0f * s);
    return x * __builtin_amdgcn_rcpf(1.0f + e);
}

#define GLDS16(gp, lp)                                                                   \
    __builtin_amdgcn_global_load_lds((const __attribute__((address_space(1))) void*)(gp), \
                                     (__attribute__((address_space(3))) void*)(lp), 16, 0, 0)

// ---------------------------------------------------------------------------
// frag_cast: fp32 W[K][N] -> bf16 B'[K/8][N][8], B'[c][n][j] = W[c*8+j][n].
// ---------------------------------------------------------------------------
__global__ __launch_bounds__(256) void frag_cast(const float* __restrict__ in,
                                                 __bf16* __restrict__ out,
                                                 int K, int N,
                                                 size_t inStride, size_t outStride) {
    in += (size_t)blockIdx.z * inStride;
    out += (size_t)blockIdx.z * outStride;
    __shared__ float tile[64][65];
    const int k0 = blockIdx.x * 64, n0 = blockIdx.y * 64;
    const int tid = threadIdx.x;
    const int r = tid >> 4, c4 = (tid & 15) * 4;
#pragma unroll
    for (int p = 0; p < 4; ++p) {
        const float4 v = *(const float4*)&in[(size_t)(k0 + r + p * 16) * N + n0 + c4];
        tile[r + p * 16][c4 + 0] = v.x;
        tile[r + p * 16][c4 + 1] = v.y;
        tile[r + p * 16][c4 + 2] = v.z;
        tile[r + p * 16][c4 + 3] = v.w;
    }
    __syncthreads();
    const int c = tid >> 5, nn0 = (tid & 31) * 2;
#pragma unroll
    for (int t = 0; t < 2; ++t) {
        const int nn = nn0 + t;
        bf16x8_t v;
#pragma unroll
        for (int j = 0; j < 8; ++j) v[j] = f2bf(tile[c * 8 + j][nn]);
        *(bf16x8_t*)&out[((size_t)(k0 >> 3) + c) * N * 8 + (size_t)(n0 + nn) * 8] = v;
    }
}

// ---------------------------------------------------------------------------
// Cast both activation tensors (same size) in one launch. out0/out1 are the
// contiguous bf16 destinations (out1 = out0 + n8each*8).
// ---------------------------------------------------------------------------
__global__ __launch_bounds__(256) void cast2_kernel(const float* __restrict__ a,
                                                    const float* __restrict__ b,
                                                    __bf16* __restrict__ out, int n8each) {
    const int i = blockIdx.x * 256 + threadIdx.x;
    if (i < 2 * n8each) {
        const float* src = (i < n8each) ? a : b;
        const size_t idx = (i < n8each) ? (size_t)i : (size_t)(i - n8each);
        const float4* p = (const float4*)(src + idx * 8);
        const float4 x = p[0], y = p[1];
        bf16x8_t v;
        v[0] = f2bf(x.x); v[1] = f2bf(x.y); v[2] = f2bf(x.z); v[3] = f2bf(x.w);
        v[4] = f2bf(y.x); v[5] = f2bf(y.y); v[6] = f2bf(y.z); v[7] = f2bf(y.w);
        *(bf16x8_t*)(out + (size_t)i * 8) = v;
    }
}

// ---------------------------------------------------------------------------
// Core bf16 GEMM tile (round-3 proven structure, 794 TF on K=2048):
// C[BMxBN at (bm,bn)] = act(A @ W + bias). A via LDS (GLDS16, XOR-swizzled
// chunks, 2 barriers/iter); W pre-packed frag-native B'[K/8][N][8] loaded
// straight to VGPRs. 2x2 waves x (2x2 mfma_f32_32x32x16_bf16).
// NOTE: explicit double-buffer pipelining of this loop REGRESSED (R4:
// 173->193us, matching learn_hip m99/m100) — do not re-add.
// ---------------------------------------------------------------------------
template <int ACT>
static __device__ __forceinline__ void gemm_core(const __bf16* __restrict__ A, int lda,
                                                 const __bf16* __restrict__ Bt, int Bn,
                                                 const float* __restrict__ bias,
                                                 __bf16* __restrict__ C, int ldc, int K,
                                                 int bm, int bn, __bf16* As) {
    const int tid = threadIdx.x;
    const int lane = tid & 63, wave = tid >> 6;
    const int wm = wave >> 1, wn = wave & 1;
    const int l = lane & 31, hi = lane >> 5;

    // A staging: LDS[row][c'] holds global chunk c' ^ (row&7); dest lane-contig.
    const int srow = tid >> 3;
    const int schunk = (tid & 7) ^ (srow & 7);
    const __bf16* ag = A + (size_t)(bm * BM + srow) * lda + schunk * 8;
    __bf16* asl = As + tid * 8;

    // A fragment read base: row = wm*64 + mi*32 + l, chunk' = (2s+hi)^(l&7)
    const int c0 = hi ^ (l & 7);
    const __bf16* base_a = As + (size_t)(wm * 64 + l) * BK;

    // B fragment base: frag(s,ni) at chunk kt*8+2s+hi, col bn*BN+wn*64+ni*32+l
    const size_t Bn8 = (size_t)Bn * 8;
    const __bf16* bbase = Bt + (size_t)hi * Bn8 + (size_t)(bn * BN + wn * 64 + l) * 8;

    f32x16_t acc[2][2] = {};

    const int nk = K / BK;
    for (int kt = 0; kt < nk; ++kt) {
        // B fragments for this K-tile: 8 coalesced global b128 loads
        bf16x8_t bfr[4][2];
        const __bf16* bp = bbase + (size_t)(kt * 8) * Bn8;
#pragma unroll
        for (int s = 0; s < 4; ++s) {
            bfr[s][0] = *(const bf16x8_t*)(bp + (size_t)(2 * s) * Bn8);
            bfr[s][1] = *(const bf16x8_t*)(bp + (size_t)(2 * s) * Bn8 + 256);
        }
        // A tile staging (4 GLDS of 16B/lane)
        GLDS16(ag, asl);
        GLDS16(ag + (size_t)32 * lda, asl + 2048);
        GLDS16(ag + (size_t)64 * lda, asl + 4096);
        GLDS16(ag + (size_t)96 * lda, asl + 6144);
        ag += BK;
        __syncthreads();  // drains GLDS + B loads together
#pragma unroll
        for (int s = 0; s < 4; ++s) {
            const int co = (c0 ^ (2 * s)) * 8;
            const bf16x8_t a0 = *(const bf16x8_t*)(base_a + co);
            const bf16x8_t a1 = *(const bf16x8_t*)(base_a + 2048 + co);
            acc[0][0] = __builtin_amdgcn_mfma_f32_32x32x16_bf16(a0, bfr[s][0], acc[0][0], 0, 0, 0);
            acc[0][1] = __builtin_amdgcn_mfma_f32_32x32x16_bf16(a0, bfr[s][1], acc[0][1], 0, 0, 0);
            acc[1][0] = __builtin_amdgcn_mfma_f32_32x32x16_bf16(a1, bfr[s][0], acc[1][0], 0, 0, 0);
            acc[1][1] = __builtin_amdgcn_mfma_f32_32x32x16_bf16(a1, bfr[s][1], acc[1][1], 0, 0, 0);
        }
        __syncthreads();
    }

    // epilogue: 32x32 C/D layout: col = lane&31, row = (reg&3) + 8*(reg>>2) + 4*hi
    const int colbase = bn * BN + wn * 64 + l;
    const int rowbase = bm * BM + wm * 64 + 4 * hi;
#pragma unroll
    for (int ni = 0; ni < 2; ++ni) {
        const int col = colbase + ni * 32;
        const float bv = bias[col];
#pragma unroll
        for (int mi = 0; mi < 2; ++mi) {
#pragma unroll
            for (int v = 0; v < 16; ++v) {
                const int row = rowbase + mi * 32 + (v & 3) + 8 * (v >> 2);
                float x = acc[mi][ni][v] + bv;
                if (ACT == 1) x = gelu_fast(x);
                C[(size_t)row * ldc + col] = f2bf(x);
            }
        }
    }
}

template <int ACT>
__global__ __launch_bounds__(256) void gemm_bt(const __bf16* __restrict__ Ab, int lda, size_t strideAe,
                                               const __bf16* __restrict__ Bb, int Bn, size_t strideBe,
                                               const float* __restrict__ biasb, size_t strideBiasE,
                                               __bf16* __restrict__ Cb, int ldc, size_t strideCe,
                                               int K) {
    __shared__ __bf16 As[BM * BK];  // 16 KB
    gemm_core<ACT>(Ab + (size_t)blockIdx.z * strideAe, lda,
                   Bb + (size_t)blockIdx.z * strideBe, Bn,
                   biasb + (size_t)blockIdx.z * strideBiasE,
                   Cb + (size_t)blockIdx.z * strideCe, ldc, K,
                   blockIdx.x, blockIdx.y, As);
}

// Both projections in one launch: z=0 visual, z=1 text. C cols [z*1024 ..].
__global__ __launch_bounds__(256) void gemm_proj(const __bf16* __restrict__ A0,
                                                 const __bf16* __restrict__ A1,
                                                 const __bf16* __restrict__ B0,
                                                 const __bf16* __restrict__ B1,
                                                 const float* __restrict__ b0,
                                                 const float* __restrict__ b1,
                                                 __bf16* __restrict__ C, int K) {
    __shared__ __bf16 As[BM * BK];
    const int z = blockIdx.z;
    gemm_core<0>(z ? A1 : A0, K, z ? B1 : B0, 1024, z ? b1 : b0,
                 C + (size_t)z * 1024, 2048, K, blockIdx.x, blockIdx.y, As);
}

// ---------------------------------------------------------------------------
// Gate: softmax(combined @ gate_w + gate_b) over E=8. One block per row.
// ---------------------------------------------------------------------------
__global__ __launch_bounds__(256) void gate_kernel(const __bf16* __restrict__ comb,
                                                   const float* __restrict__ gw,
                                                   const float* __restrict__ gb,
                                                   float* __restrict__ gate) {
    const int b = blockIdx.x, tid = threadIdx.x;
    const int lane = tid & 63, wv = tid >> 6;
    const __bf16* row = comb + (size_t)b * 2048;
    float a[8] = {0, 0, 0, 0, 0, 0, 0, 0};
    for (int k = tid; k < 2048; k += 256) {
        const float c = bf2f(row[k]);
        const float4* g4 = (const float4*)(gw + (size_t)k * 8);
        const float4 x = g4[0], y = g4[1];
        a[0] += c * x.x; a[1] += c * x.y; a[2] += c * x.z; a[3] += c * x.w;
        a[4] += c * y.x; a[5] += c * y.y; a[6] += c * y.z; a[7] += c * y.w;
    }
#pragma unroll
    for (int j = 0; j < 8; ++j)
        for (int off = 32; off; off >>= 1) a[j] += __shfl_down(a[j], off, 64);
    __shared__ float red[4][8];
    if (lane == 0) {
#pragma unroll
        for (int j = 0; j < 8; ++j) red[wv][j] = a[j];
    }
    __syncthreads();
    if (tid == 0) {
        float l[8];
        float m = -1e30f;
        for (int j = 0; j < 8; ++j) {
            l[j] = red[0][j] + red[1][j] + red[2][j] + red[3][j] + gb[j];
            m = fmaxf(m, l[j]);
        }
        float s = 0.f;
        for (int j = 0; j < 8; ++j) { l[j] = expf(l[j] - m); s += l[j]; }
        const float inv = 1.0f / s;
        for (int j = 0; j < 8; ++j) gate[(size_t)b * 8 + j] = l[j] * inv;
    }
}

// ---------------------------------------------------------------------------
// Fused LayerNorm + gated expert reduction. One block per row b.
// All Eg expert rows prefetched up front (overlapped loads); single barrier
// via sS[4][8] staging instead of 2 barriers per expert.
// ---------------------------------------------------------------------------
__global__ __launch_bounds__(256) void ln_out_kernel(const __bf16* __restrict__ h2,
                                                     const float* __restrict__ gate,
                                                     const float* __restrict__ lng,
                                                     const float* __restrict__ lnb,
                                                     float* __restrict__ out,
                                                     int Eg, int g0, int accum) {
    const int b = blockIdx.x;
    const int tid = threadIdx.x;
    const int lane = tid & 63, wv = tid >> 6;
    const int d0 = tid * 4;
    __shared__ float sS[4][8], sSS[4][8];
    float* orow = out + (size_t)b * 1024 + d0;
    float o0, o1, o2, o3;
    if (accum) {
        const float4 p = *(const float4*)orow;
        o0 = p.x; o1 = p.y; o2 = p.z; o3 = p.w;
    } else {
        o0 = o1 = o2 = o3 = 0.f;
    }
    // prefetch all expert rows (loads issue back-to-back, latency overlapped)
    float v[8][4];
#pragma unroll
    for (int e = 0; e < 8; ++e)
        if (e < Eg) {
            const bf16x4_t hv = *(const bf16x4_t*)(h2 + ((size_t)e * 8192 + b) * 1024 + d0);
            v[e][0] = bf2f(hv[0]); v[e][1] = bf2f(hv[1]);
            v[e][2] = bf2f(hv[2]); v[e][3] = bf2f(hv[3]);
        }
#pragma unroll
    for (int e = 0; e < 8; ++e)
        if (e < Eg) {
            float s = v[e][0] + v[e][1] + v[e][2] + v[e][3];
            float ss = v[e][0] * v[e][0] + v[e][1] * v[e][1] + v[e][2] * v[e][2] + v[e][3] * v[e][3];
            for (int off = 32; off; off >>= 1) {
                s += __shfl_down(s, off, 64);
                ss += __shfl_down(ss, off, 64);
            }
            if (lane == 0) { sS[wv][e] = s; sSS[wv][e] = ss; }
        }
    __syncthreads();
#pragma unroll
    for (int e = 0; e < 8; ++e)
        if (e < Eg) {
            const float S = sS[0][e] + sS[1][e] + sS[2][e] + sS[3][e];
            const float SS = sSS[0][e] + sSS[1][e] + sSS[2][e] + sSS[3][e];
            const float mu = S * (1.0f / 1024.0f);
            const float var = SS * (1.0f / 1024.0f) - mu * mu;
            const float rstd = rsqrtf(var + 1e-5f);
            const float w = gate[(size_t)b * 8 + g0 + e];
            const float4 gg = *(const float4*)(lng + (size_t)(g0 + e) * 1024 + d0);
            const float4 bb = *(const float4*)(lnb + (size_t)(g0 + e) * 1024 + d0);
            o0 += w * ((v[e][0] - mu) * rstd * gg.x + bb.x);
            o1 += w * ((v[e][1] - mu) * rstd * gg.y + bb.y);
            o2 += w * ((v[e][2] - mu) * rstd * gg.z + bb.z);
            o3 += w * ((v[e][3] - mu) * rstd * gg.w + bb.w);
        }
    *(float4*)orow = make_float4(o0, o1, o2, o3);
}

// ---------------------------------------------------------------------------
extern "C" void kernel_launch(void* const* d_in, const int* in_sizes, int n_in,
                              void* d_out, int out_size, void* d_ws, size_t ws_size,
                              hipStream_t stream) {
    (void)in_sizes; (void)n_in; (void)out_size;
    const float* visual = (const float*)d_in[0];
    const float* text   = (const float*)d_in[1];
    const float* vis_w  = (const float*)d_in[2];
    const float* vis_b  = (const float*)d_in[3];
    const float* txt_w  = (const float*)d_in[4];
    const float* txt_b  = (const float*)d_in[5];
    const float* gate_w = (const float*)d_in[6];
    const float* gate_b = (const float*)d_in[7];
    const float* w1     = (const float*)d_in[8];
    const float* b1     = (const float*)d_in[9];
    const float* w2     = (const float*)d_in[10];
    const float* b2     = (const float*)d_in[11];
    const float* ln_g   = (const float*)d_in[12];
    const float* ln_b   = (const float*)d_in[13];
    float* out = (float*)d_out;

    const size_t B = 8192, DV = 768, D = 1024, G = 2048, E = 8;

    char* ws = (char*)d_ws;
    size_t o = 0;
    auto alloc = [&](size_t bytes) { size_t r = o; o = (o + bytes + 255) & ~(size_t)255; return r; };
    const size_t off_viswt = alloc(DV * D * 2);
    const size_t off_txtwt = alloc(DV * D * 2);
    const size_t off_w1t   = alloc(E * G * D * 2);
    const size_t off_w2t   = alloc(E * D * D * 2);
    const size_t off_comb  = alloc(B * G * 2);
    const size_t off_gate  = alloc(B * E * 4);
    const size_t fixedEnd = o;
    const size_t inpBytes = 2 * B * DV * 2;  // bf16 visual+text, aliased under h1 region

    int Eg = 1;
    {
        const int cand[4] = {8, 4, 2, 1};
        for (int c = 0; c < 4; ++c) {
            size_t h = (size_t)cand[c] * B * D * 2;
            size_t r1 = h > inpBytes ? h : inpBytes;
            r1 = (r1 + 255) & ~(size_t)255;
            const size_t need = fixedEnd + r1 + h;
            if (need <= ws_size || cand[c] == 1) { Eg = cand[c]; break; }
        }
    }
    const size_t h1bytes = (size_t)Eg * B * D * 2;
    size_t r1sz = h1bytes > inpBytes ? h1bytes : inpBytes;
    r1sz = (r1sz + 255) & ~(size_t)255;
    const size_t off_r1 = fixedEnd;
    const size_t off_h2 = off_r1 + r1sz;

    __bf16* viswt = (__bf16*)(ws + off_viswt);
    __bf16* txtwt = (__bf16*)(ws + off_txtwt);
    __bf16* w1t   = (__bf16*)(ws + off_w1t);
    __bf16* w2t   = (__bf16*)(ws + off_w2t);
    __bf16* comb  = (__bf16*)(ws + off_comb);
    float*  gate  = (float*)(ws + off_gate);
    __bf16* vis_bf = (__bf16*)(ws + off_r1);
    __bf16* txt_bf = vis_bf + B * DV;
    __bf16* h1    = (__bf16*)(ws + off_r1);   // aliases bf16 inputs (dead after proj GEMMs)
    __bf16* h2    = (__bf16*)(ws + off_h2);

    // 1) weight pack+cast to frag-native bf16 [K/8][N][8]
    frag_cast<<<dim3(DV / 64, D / 64, 1), 256, 0, stream>>>(vis_w, viswt, (int)DV, (int)D, 0, 0);
    frag_cast<<<dim3(DV / 64, D / 64, 1), 256, 0, stream>>>(txt_w, txtwt, (int)DV, (int)D, 0, 0);
    frag_cast<<<dim3(G / 64, D / 64, E), 256, 0, stream>>>(w1, w1t, (int)G, (int)D, G * D, G * D);
    frag_cast<<<dim3(D / 64, D / 64, E), 256, 0, stream>>>(w2, w2t, (int)D, (int)D, D * D, D * D);

    // 2) activation cast to bf16 (both tensors, one launch)
    const int n8 = (int)(B * DV / 8);
    cast2_kernel<<<(2 * n8 + 255) / 256, 256, 0, stream>>>(visual, text, vis_bf, n8);

    // 3) both projections -> combined bf16 [B][2048], one launch
    gemm_proj<<<dim3(B / BM, D / BN, 2), 256, 0, stream>>>(vis_bf, txt_bf, viswt, txtwt,
                                                           vis_b, txt_b, comb, (int)DV);

    // 4) gate softmax
    gate_kernel<<<(int)B, 256, 0, stream>>>(comb, gate_w, gate_b, gate);

    // 5) experts in groups of Eg
    const int ng = 8 / Eg;
    for (int g = 0; g < ng; ++g) {
        const int g0 = g * Eg;
        gemm_bt<1><<<dim3(B / BM, D / BN, Eg), 256, 0, stream>>>(
            comb, (int)G, 0, w1t + (size_t)g0 * G * D, (int)D, G * D,
            b1 + (size_t)g0 * D, D, h1, (int)D, B * D, (int)G);
        gemm_bt<0><<<dim3(B / BM, D / BN, Eg), 256, 0, stream>>>(
            h1, (int)D, B * D, w2t + (size_t)g0 * D * D, (int)D, D * D,
            b2 + (size_t)g0 * D, D, h2, (int)D, B * D, (int)D);
        ln_out_kernel<<<(int)B, 256, 0, stream>>>(h2, gate, ln_g, ln_b, out, Eg, g0, g > 0 ? 1 : 0);
    }
}

// Round 6
// 769.058 us; speedup vs baseline: 1.1503x; 1.1503x over previous
//
#include <hip/hip_runtime.h>
#include <hip/hip_bf16.h>
#include <math.h>

#define BM 128
#define BN 128
#define BK 64

typedef __bf16 bf16x8_t __attribute__((ext_vector_type(8)));
typedef __bf16 bf16x4_t __attribute__((ext_vector_type(4)));
typedef float f32x16_t __attribute__((ext_vector_type(16)));

static __device__ __forceinline__ float bf2f(__bf16 b) {
    unsigned short s = __builtin_bit_cast(unsigned short, b);
    unsigned int u = ((unsigned int)s) << 16;
    return __builtin_bit_cast(float, u);
}
static __device__ __forceinline__ __bf16 f2bf(float f) {
    unsigned int u = __builtin_bit_cast(unsigned int, f);
    unsigned int r = (u + 0x7fffu + ((u >> 16) & 1u)) >> 16;
    return __builtin_bit_cast(__bf16, (unsigned short)r);
}
// GELU tanh-form, |err vs exact| ~1e-3 << 4e-2 tolerance.
static __device__ __forceinline__ float gelu_fast(float x) {
    const float s = x * (0.7978845608f + 0.0356774081f * x * x);
    const float e = __expf(-2.0f * s);
    return x * __builtin_amdgcn_rcpf(1.0f + e);
}

#define GLDS16(gp, lp)                                                                   \
    __builtin_amdgcn_global_load_lds((const __attribute__((address_space(1))) void*)(gp), \
                                     (__attribute__((address_space(3))) void*)(lp), 16, 0, 0)

// ---------------------------------------------------------------------------
// frag_cast: fp32 W[K][N] -> bf16 B'[K/8][N][8], B'[c][n][j] = W[c*8+j][n].
// ---------------------------------------------------------------------------
__global__ __launch_bounds__(256) void frag_cast(const float* __restrict__ in,
                                                 __bf16* __restrict__ out,
                                                 int K, int N,
                                                 size_t inStride, size_t outStride) {
    in += (size_t)blockIdx.z * inStride;
    out += (size_t)blockIdx.z * outStride;
    __shared__ float tile[64][65];
    const int k0 = blockIdx.x * 64, n0 = blockIdx.y * 64;
    const int tid = threadIdx.x;
    const int r = tid >> 4, c4 = (tid & 15) * 4;
#pragma unroll
    for (int p = 0; p < 4; ++p) {
        const float4 v = *(const float4*)&in[(size_t)(k0 + r + p * 16) * N + n0 + c4];
        tile[r + p * 16][c4 + 0] = v.x;
        tile[r + p * 16][c4 + 1] = v.y;
        tile[r + p * 16][c4 + 2] = v.z;
        tile[r + p * 16][c4 + 3] = v.w;
    }
    __syncthreads();
    const int c = tid >> 5, nn0 = (tid & 31) * 2;
#pragma unroll
    for (int t = 0; t < 2; ++t) {
        const int nn = nn0 + t;
        bf16x8_t v;
#pragma unroll
        for (int j = 0; j < 8; ++j) v[j] = f2bf(tile[c * 8 + j][nn]);
        *(bf16x8_t*)&out[((size_t)(k0 >> 3) + c) * N * 8 + (size_t)(n0 + nn) * 8] = v;
    }
}

// ---------------------------------------------------------------------------
// Cast two equal-size fp32 tensors to one contiguous bf16 buffer.
// ---------------------------------------------------------------------------
__global__ __launch_bounds__(256) void cast2_kernel(const float* __restrict__ a,
                                                    const float* __restrict__ b,
                                                    __bf16* __restrict__ out, int n8each) {
    const int i = blockIdx.x * 256 + threadIdx.x;
    if (i < 2 * n8each) {
        const float* src = (i < n8each) ? a : b;
        const size_t idx = (i < n8each) ? (size_t)i : (size_t)(i - n8each);
        const float4* p = (const float4*)(src + idx * 8);
        const float4 x = p[0], y = p[1];
        bf16x8_t v;
        v[0] = f2bf(x.x); v[1] = f2bf(x.y); v[2] = f2bf(x.z); v[3] = f2bf(x.w);
        v[4] = f2bf(y.x); v[5] = f2bf(y.y); v[6] = f2bf(y.z); v[7] = f2bf(y.w);
        *(bf16x8_t*)(out + (size_t)i * 8) = v;
    }
}

// ---------------------------------------------------------------------------
// cast_acat: visual[8192][768] + text[8192][768] fp32 -> acat[8192][1536] bf16
// with row = [vis row | txt row]. 8 elems/thread; 8 | 768 so no straddle.
// ---------------------------------------------------------------------------
__global__ __launch_bounds__(256) void cast_acat(const float* __restrict__ vis,
                                                 const float* __restrict__ txt,
                                                 __bf16* __restrict__ out, int total8) {
    const int i = blockIdx.x * 256 + threadIdx.x;
    if (i < total8) {
        const int r = i / 192;           // 1536/8 chunks per row
        const int c8 = i - r * 192;
        const float* src = (c8 < 96) ? vis + (size_t)r * 768 + (size_t)c8 * 8
                                     : txt + (size_t)r * 768 + (size_t)(c8 - 96) * 8;
        const float4* p = (const float4*)src;
        const float4 x = p[0], y = p[1];
        bf16x8_t v;
        v[0] = f2bf(x.x); v[1] = f2bf(x.y); v[2] = f2bf(x.z); v[3] = f2bf(x.w);
        v[4] = f2bf(y.x); v[5] = f2bf(y.y); v[6] = f2bf(y.z); v[7] = f2bf(y.w);
        *(bf16x8_t*)(out + (size_t)i * 8) = v;
    }
}

// ---------------------------------------------------------------------------
// Core bf16 GEMM tile (round-3 proven structure, 794 TF @K=2048):
// C[BMxBN at (bm,bn)] = act(A @ W + bias). A via LDS (GLDS16, XOR-swizzled
// chunks, 2 barriers/iter); W pre-packed frag-native B'[K/8][N][8] -> VGPRs.
// 2x2 waves x (2x2 mfma_f32_32x32x16_bf16).
// NOTE: explicit double-buffer pipelining REGRESSED (R4: 173->193us, matches
// learn_hip m99/m100) — do not re-add.
// PACK=1: no bias/act, store C in frag-native packed layout [M/8][N][8].
// ---------------------------------------------------------------------------
template <int ACT, int PACK>
static __device__ __forceinline__ void gemm_core(const __bf16* __restrict__ A, int lda,
                                                 const __bf16* __restrict__ Bt, int Bn,
                                                 const float* __restrict__ bias,
                                                 __bf16* __restrict__ C, int ldc, int K,
                                                 int bm, int bn, __bf16* As) {
    const int tid = threadIdx.x;
    const int lane = tid & 63, wave = tid >> 6;
    const int wm = wave >> 1, wn = wave & 1;
    const int l = lane & 31, hi = lane >> 5;

    // A staging: LDS[row][c'] holds global chunk c' ^ (row&7); dest lane-contig.
    const int srow = tid >> 3;
    const int schunk = (tid & 7) ^ (srow & 7);
    const __bf16* ag = A + (size_t)(bm * BM + srow) * lda + schunk * 8;
    __bf16* asl = As + tid * 8;

    // A fragment read base: row = wm*64 + mi*32 + l, chunk' = (2s+hi)^(l&7)
    const int c0 = hi ^ (l & 7);
    const __bf16* base_a = As + (size_t)(wm * 64 + l) * BK;

    // B fragment base: frag(s,ni) at chunk kt*8+2s+hi, col bn*BN+wn*64+ni*32+l
    const size_t Bn8 = (size_t)Bn * 8;
    const __bf16* bbase = Bt + (size_t)hi * Bn8 + (size_t)(bn * BN + wn * 64 + l) * 8;

    f32x16_t acc[2][2] = {};

    const int nk = K / BK;
    for (int kt = 0; kt < nk; ++kt) {
        bf16x8_t bfr[4][2];
        const __bf16* bp = bbase + (size_t)(kt * 8) * Bn8;
#pragma unroll
        for (int s = 0; s < 4; ++s) {
            bfr[s][0] = *(const bf16x8_t*)(bp + (size_t)(2 * s) * Bn8);
            bfr[s][1] = *(const bf16x8_t*)(bp + (size_t)(2 * s) * Bn8 + 256);
        }
        GLDS16(ag, asl);
        GLDS16(ag + (size_t)32 * lda, asl + 2048);
        GLDS16(ag + (size_t)64 * lda, asl + 4096);
        GLDS16(ag + (size_t)96 * lda, asl + 6144);
        ag += BK;
        __syncthreads();
#pragma unroll
        for (int s = 0; s < 4; ++s) {
            const int co = (c0 ^ (2 * s)) * 8;
            const bf16x8_t a0 = *(const bf16x8_t*)(base_a + co);
            const bf16x8_t a1 = *(const bf16x8_t*)(base_a + 2048 + co);
            acc[0][0] = __builtin_amdgcn_mfma_f32_32x32x16_bf16(a0, bfr[s][0], acc[0][0], 0, 0, 0);
            acc[0][1] = __builtin_amdgcn_mfma_f32_32x32x16_bf16(a0, bfr[s][1], acc[0][1], 0, 0, 0);
            acc[1][0] = __builtin_amdgcn_mfma_f32_32x32x16_bf16(a1, bfr[s][0], acc[1][0], 0, 0, 0);
            acc[1][1] = __builtin_amdgcn_mfma_f32_32x32x16_bf16(a1, bfr[s][1], acc[1][1], 0, 0, 0);
        }
        __syncthreads();
    }

    // epilogue: 32x32 C/D layout: col = lane&31, row = (reg&3) + 8*(reg>>2) + 4*hi
    const int colbase = bn * BN + wn * 64 + l;
    const int rowbase = bm * BM + wm * 64 + 4 * hi;
#pragma unroll
    for (int ni = 0; ni < 2; ++ni) {
        const int col = colbase + ni * 32;
        const float bv = PACK ? 0.0f : bias[col];
#pragma unroll
        for (int mi = 0; mi < 2; ++mi) {
#pragma unroll
            for (int v = 0; v < 16; ++v) {
                const int row = rowbase + mi * 32 + (v & 3) + 8 * (v >> 2);
                float x = acc[mi][ni][v] + bv;
                if (ACT == 1) x = gelu_fast(x);
                if (PACK) {
                    C[((size_t)(row >> 3)) * (size_t)ldc * 8 + (size_t)col * 8 + (row & 7)] = f2bf(x);
                } else {
                    C[(size_t)row * ldc + col] = f2bf(x);
                }
            }
        }
    }
}

template <int ACT>
__global__ __launch_bounds__(256) void gemm_bt(const __bf16* __restrict__ Ab, int lda, size_t strideAe,
                                               const __bf16* __restrict__ Bb, int Bn, size_t strideBe,
                                               const float* __restrict__ biasb, size_t strideBiasE,
                                               __bf16* __restrict__ Cb, int ldc, size_t strideCe,
                                               int K) {
    __shared__ __bf16 As[BM * BK];  // 16 KB
    gemm_core<ACT, 0>(Ab + (size_t)blockIdx.z * strideAe, lda,
                      Bb + (size_t)blockIdx.z * strideBe, Bn,
                      biasb + (size_t)blockIdx.z * strideBiasE,
                      Cb + (size_t)blockIdx.z * strideCe, ldc, K,
                      blockIdx.x, blockIdx.y, As);
}

// Weight pre-multiply: W1cat[e] rows [0,768) = vis_w@w1_top[e], rows [768,1536)
// = txt_w@w1_bot[e]; output written frag-packed for direct use as B in w1 GEMM.
// z = e + 8*hf; M=768, N=1024, K=1024.
__global__ __launch_bounds__(256) void gemm_premul(const __bf16* __restrict__ wbf,
                                                   const __bf16* __restrict__ w1t,
                                                   __bf16* __restrict__ w1cat) {
    __shared__ __bf16 As[BM * BK];
    const int e = blockIdx.z & 7, hf = blockIdx.z >> 3;
    gemm_core<0, 1>(wbf + (size_t)hf * 768 * 1024, 1024,
                    w1t + (size_t)e * 2048 * 1024 + (size_t)hf * 128 * 1024 * 8, 1024,
                    nullptr,
                    w1cat + (size_t)e * 1536 * 1024 + (size_t)hf * 96 * 1024 * 8, 1024, 1024,
                    blockIdx.x, blockIdx.y, As);
}

// ---------------------------------------------------------------------------
// b1t[e][n] = b1[e][n] + sum_d bcat[d]*w1[e][d][n], bcat=[vis_b|txt_b].
// grid (nchunk=4, e=8, dquarter=4); atomicAdd into pre-zeroed b1t.
// ---------------------------------------------------------------------------
__global__ __launch_bounds__(256) void bias1_kernel(const float* __restrict__ w1,
                                                    const float* __restrict__ vis_b,
                                                    const float* __restrict__ txt_b,
                                                    const float* __restrict__ b1,
                                                    float* __restrict__ b1t) {
    const int n = blockIdx.x * 256 + threadIdx.x;
    const int e = blockIdx.y;
    const int d0 = blockIdx.z * 512;
    float acc = (blockIdx.z == 0) ? b1[(size_t)e * 1024 + n] : 0.0f;
#pragma unroll 4
    for (int d = d0; d < d0 + 512; ++d) {
        const float bv = (d < 1024) ? vis_b[d] : txt_b[d - 1024];
        acc += bv * w1[((size_t)e * 2048 + d) * 1024 + n];
    }
    atomicAdd(&b1t[(size_t)e * 1024 + n], acc);
}

// ---------------------------------------------------------------------------
// Gcat[v][j] (v<1536) = sum_d w_row[v][d]*gw[dglob][j]; block 1536 computes
// bg~[j] = sum_d bcat[d]*gw[d][j] + gate_b[j], stored at Gcat+1536*8.
// ---------------------------------------------------------------------------
__global__ __launch_bounds__(256) void gcat_kernel(const float* __restrict__ vis_w,
                                                   const float* __restrict__ txt_w,
                                                   const float* __restrict__ vis_b,
                                                   const float* __restrict__ txt_b,
                                                   const float* __restrict__ gw,
                                                   const float* __restrict__ gb,
                                                   float* __restrict__ gcat) {
    const int v = blockIdx.x, tid = threadIdx.x;
    const int lane = tid & 63, wv = tid >> 6;
    float a[8] = {0, 0, 0, 0, 0, 0, 0, 0};
    if (v < 1536) {
        const float* wr = (v < 768) ? vis_w + (size_t)v * 1024 : txt_w + (size_t)(v - 768) * 1024;
        const int dbase = (v < 768) ? 0 : 1024;
        for (int d = tid; d < 1024; d += 256) {
            const float c = wr[d];
            const float4* g4 = (const float4*)(gw + (size_t)(dbase + d) * 8);
            const float4 x = g4[0], y = g4[1];
            a[0] += c * x.x; a[1] += c * x.y; a[2] += c * x.z; a[3] += c * x.w;
            a[4] += c * y.x; a[5] += c * y.y; a[6] += c * y.z; a[7] += c * y.w;
        }
    } else {
        for (int d = tid; d < 2048; d += 256) {
            const float c = (d < 1024) ? vis_b[d] : txt_b[d - 1024];
            const float4* g4 = (const float4*)(gw + (size_t)d * 8);
            const float4 x = g4[0], y = g4[1];
            a[0] += c * x.x; a[1] += c * x.y; a[2] += c * x.z; a[3] += c * x.w;
            a[4] += c * y.x; a[5] += c * y.y; a[6] += c * y.z; a[7] += c * y.w;
        }
    }
#pragma unroll
    for (int j = 0; j < 8; ++j)
        for (int off = 32; off; off >>= 1) a[j] += __shfl_down(a[j], off, 64);
    __shared__ float red[4][8];
    if (lane == 0) {
#pragma unroll
        for (int j = 0; j < 8; ++j) red[wv][j] = a[j];
    }
    __syncthreads();
    if (tid < 8) {
        float s = red[0][tid] + red[1][tid] + red[2][tid] + red[3][tid];
        if (v == 1536) s += gb[tid];
        gcat[(size_t)v * 8 + tid] = s;
    }
}

// ---------------------------------------------------------------------------
// Gate: softmax(acat @ Gcat + bg~) over E=8. One block per row.
// ---------------------------------------------------------------------------
__global__ __launch_bounds__(256) void gate_kernel(const __bf16* __restrict__ acat,
                                                   const float* __restrict__ gcat,
                                                   float* __restrict__ gate) {
    const int b = blockIdx.x, tid = threadIdx.x;
    const int lane = tid & 63, wv = tid >> 6;
    const __bf16* row = acat + (size_t)b * 1536;
    float a[8] = {0, 0, 0, 0, 0, 0, 0, 0};
    for (int k = tid; k < 1536; k += 256) {
        const float c = bf2f(row[k]);
        const float4* g4 = (const float4*)(gcat + (size_t)k * 8);
        const float4 x = g4[0], y = g4[1];
        a[0] += c * x.x; a[1] += c * x.y; a[2] += c * x.z; a[3] += c * x.w;
        a[4] += c * y.x; a[5] += c * y.y; a[6] += c * y.z; a[7] += c * y.w;
    }
#pragma unroll
    for (int j = 0; j < 8; ++j)
        for (int off = 32; off; off >>= 1) a[j] += __shfl_down(a[j], off, 64);
    __shared__ float red[4][8];
    if (lane == 0) {
#pragma unroll
        for (int j = 0; j < 8; ++j) red[wv][j] = a[j];
    }
    __syncthreads();
    if (tid == 0) {
        const float* bg = gcat + 1536 * 8;
        float l[8];
        float m = -1e30f;
        for (int j = 0; j < 8; ++j) {
            l[j] = red[0][j] + red[1][j] + red[2][j] + red[3][j] + bg[j];
            m = fmaxf(m, l[j]);
        }
        float s = 0.f;
        for (int j = 0; j < 8; ++j) { l[j] = expf(l[j] - m); s += l[j]; }
        const float inv = 1.0f / s;
        for (int j = 0; j < 8; ++j) gate[(size_t)b * 8 + j] = l[j] * inv;
    }
}

// ---------------------------------------------------------------------------
// Fused LayerNorm + gated expert reduction (R3-proven form). One block/row.
// ---------------------------------------------------------------------------
__global__ __launch_bounds__(256) void ln_out_kernel(const __bf16* __restrict__ h2,
                                                     const float* __restrict__ gate,
                                                     const float* __restrict__ lng,
                                                     const float* __restrict__ lnb,
                                                     float* __restrict__ out,
                                                     int Eg, int g0, int accum) {
    const int b = blockIdx.x;
    const int tid = threadIdx.x;
    const int lane = tid & 63, wv = tid >> 6;
    const int d0 = tid * 4;
    __shared__ float sS[4], sSS[4];
    float* orow = out + (size_t)b * 1024 + d0;
    float o0, o1, o2, o3;
    if (accum) {
        const float4 p = *(const float4*)orow;
        o0 = p.x; o1 = p.y; o2 = p.z; o3 = p.w;
    } else {
        o0 = o1 = o2 = o3 = 0.f;
    }
    for (int e = 0; e < Eg; ++e) {
        const __bf16* hp = h2 + ((size_t)e * 8192 + b) * 1024 + d0;
        const bf16x4_t hv = *(const bf16x4_t*)hp;
        const float v0 = bf2f(hv[0]), v1 = bf2f(hv[1]), v2 = bf2f(hv[2]), v3 = bf2f(hv[3]);
        float s = v0 + v1 + v2 + v3;
        float ss = v0 * v0 + v1 * v1 + v2 * v2 + v3 * v3;
        for (int off = 32; off; off >>= 1) {
            s += __shfl_down(s, off, 64);
            ss += __shfl_down(ss, off, 64);
        }
        if (lane == 0) { sS[wv] = s; sSS[wv] = ss; }
        __syncthreads();
        const float S = sS[0] + sS[1] + sS[2] + sS[3];
        const float SS = sSS[0] + sSS[1] + sSS[2] + sSS[3];
        __syncthreads();
        const float mu = S * (1.0f / 1024.0f);
        const float var = SS * (1.0f / 1024.0f) - mu * mu;
        const float rstd = rsqrtf(var + 1e-5f);
        const float w = gate[(size_t)b * 8 + g0 + e];
        const float4 gg = *(const float4*)(lng + (size_t)(g0 + e) * 1024 + d0);
        const float4 bb = *(const float4*)(lnb + (size_t)(g0 + e) * 1024 + d0);
        o0 += w * ((v0 - mu) * rstd * gg.x + bb.x);
        o1 += w * ((v1 - mu) * rstd * gg.y + bb.y);
        o2 += w * ((v2 - mu) * rstd * gg.z + bb.z);
        o3 += w * ((v3 - mu) * rstd * gg.w + bb.w);
    }
    *(float4*)orow = make_float4(o0, o1, o2, o3);
}

// ---------------------------------------------------------------------------
extern "C" void kernel_launch(void* const* d_in, const int* in_sizes, int n_in,
                              void* d_out, int out_size, void* d_ws, size_t ws_size,
                              hipStream_t stream) {
    (void)in_sizes; (void)n_in; (void)out_size;
    const float* visual = (const float*)d_in[0];
    const float* text   = (const float*)d_in[1];
    const float* vis_w  = (const float*)d_in[2];
    const float* vis_b  = (const float*)d_in[3];
    const float* txt_w  = (const float*)d_in[4];
    const float* txt_b  = (const float*)d_in[5];
    const float* gate_w = (const float*)d_in[6];
    const float* gate_b = (const float*)d_in[7];
    const float* w1     = (const float*)d_in[8];
    const float* b1     = (const float*)d_in[9];
    const float* w2     = (const float*)d_in[10];
    const float* b2     = (const float*)d_in[11];
    const float* ln_g   = (const float*)d_in[12];
    const float* ln_b   = (const float*)d_in[13];
    float* out = (float*)d_out;

    const size_t B = 8192, DV = 768, D = 1024, G = 2048, E = 8, KC = 1536;

    char* ws = (char*)d_ws;
    size_t o = 0;
    auto alloc = [&](size_t bytes) { size_t r = o; o = (o + bytes + 255) & ~(size_t)255; return r; };
    const size_t off_wbf   = alloc(2 * DV * D * 2);        // vis_w_bf | txt_w_bf
    const size_t off_w1cat = alloc(E * KC * D * 2);        // fused W1, frag-packed
    const size_t off_w2t   = alloc(E * D * D * 2);
    const size_t off_b1t   = alloc(E * D * 4);
    const size_t off_gcat  = alloc((KC * E + E) * 4);
    const size_t off_gate  = alloc(B * E * 4);
    const size_t off_acat  = alloc(B * KC * 2);
    const size_t fixedEnd = o;
    const size_t w1tBytes = E * G * D * 2;  // 33.5 MB, dead after premul

    int Eg = 1;
    {
        const int cand[4] = {8, 4, 2, 1};
        for (int c = 0; c < 4; ++c) {
            size_t h2b = 2 * (size_t)cand[c] * B * D * 2;
            size_t dyn = h2b > w1tBytes ? h2b : w1tBytes;
            if (fixedEnd + dyn <= ws_size || cand[c] == 1) { Eg = cand[c]; break; }
        }
    }

    __bf16* wbf   = (__bf16*)(ws + off_wbf);
    __bf16* w1cat = (__bf16*)(ws + off_w1cat);
    __bf16* w2t   = (__bf16*)(ws + off_w2t);
    float*  b1t   = (float*)(ws + off_b1t);
    float*  gcat  = (float*)(ws + off_gcat);
    float*  gate  = (float*)(ws + off_gate);
    __bf16* acat  = (__bf16*)(ws + off_acat);
    __bf16* w1t   = (__bf16*)(ws + fixedEnd);              // aliased: dead after premul
    __bf16* h1    = (__bf16*)(ws + fixedEnd);              // overwrites w1t in expert loop
    __bf16* h2    = h1 + (size_t)Eg * B * D;

    // 1) casts: weights (vis_w|txt_w row-major bf16) and activations (acat)
    const int nw8 = (int)(DV * D / 8);
    cast2_kernel<<<(2 * nw8 + 255) / 256, 256, 0, stream>>>(vis_w, txt_w, wbf, nw8);
    const int na8 = (int)(B * KC / 8);
    cast_acat<<<(na8 + 255) / 256, 256, 0, stream>>>(visual, text, acat, na8);

    // 2) frag-pack w1 (B input of premul) and w2
    frag_cast<<<dim3(G / 64, D / 64, E), 256, 0, stream>>>(w1, w1t, (int)G, (int)D, G * D, G * D);
    frag_cast<<<dim3(D / 64, D / 64, E), 256, 0, stream>>>(w2, w2t, (int)D, (int)D, D * D, D * D);

    // 3) weight pre-multiply: W1cat = [vis_w@w1_top ; txt_w@w1_bot], packed
    gemm_premul<<<dim3(768 / BM, D / BN, 16), 256, 0, stream>>>(wbf, w1t, w1cat);

    // 4) fused biases: b1t = b1 + bcat@w1 ; Gcat = [vis_w;txt_w]@gw (+bg~)
    hipMemsetAsync(b1t, 0, E * D * 4, stream);
    bias1_kernel<<<dim3(4, 8, 4), 256, 0, stream>>>(w1, vis_b, txt_b, b1, b1t);
    gcat_kernel<<<1537, 256, 0, stream>>>(vis_w, txt_w, vis_b, txt_b, gate_w, gate_b, gcat);

    // 5) gate softmax from acat
    gate_kernel<<<(int)B, 256, 0, stream>>>(acat, gcat, gate);

    // 6) experts in groups of Eg: h1 = gelu(acat@W1cat + b1t); h2 = h1@w2 + b2; LN+reduce
    const int ng = 8 / Eg;
    for (int g = 0; g < ng; ++g) {
        const int g0 = g * Eg;
        gemm_bt<1><<<dim3(B / BM, D / BN, Eg), 256, 0, stream>>>(
            acat, (int)KC, 0, w1cat + (size_t)g0 * KC * D, (int)D, KC * D,
            b1t + (size_t)g0 * D, D, h1, (int)D, B * D, (int)KC);
        gemm_bt<0><<<dim3(B / BM, D / BN, Eg), 256, 0, stream>>>(
            h1, (int)D, B * D, w2t + (size_t)g0 * D * D, (int)D, D * D,
            b2 + (size_t)g0 * D, D, h2, (int)D, B * D, (int)D);
        ln_out_kernel<<<(int)B, 256, 0, stream>>>(h2, gate, ln_g, ln_b, out, Eg, g0, g > 0 ? 1 : 0);
    }
}